// Round 12
// baseline (36.278 us; speedup 1.0000x reference)
//
#include <hip/hip_runtime.h>

// Overlap-add: y[b, f*256 + c] += x[b, c, f]
// x: [16, 1024, 2048] f32, y: [16, 525056] f32
// WIN/HOP = 4 -> y[b, g*256 + r] = sum_{k=0}^{3} x[b, k*256 + r, g - k]
//
// R12 = R11 structure (barrier-free per-wave pipeline, sequential tile walk,
// wave owns rows 4w..4w+3, producer == consumer) with DOUBLED stream count:
// NBUF=2 / DEPTH=1 -> 32 KB LDS -> 4 blocks/CU = 16 waves/CU (vs 8 in all
// prior rounds). Grid = quarter(4) x b(16) x rsp(16) = 1024 blocks, each
// walking 8-9 sequential tiles. Isolates "per-CU supply cap" vs "per-stream
// service cap".

constexpr int BATCH   = 16;
constexpr int WIN     = 1024;
constexpr int HOP     = 256;
constexpr int NF      = 2048;                       // frames
constexpr int OUT_LEN = (NF - 1) * HOP + WIN;       // 525056
constexpr int GTOT    = OUT_LEN / HOP;              // 2051
constexpr int FT      = 64;                         // g-values per item
constexpr int NT      = (GTOT + FT - 1) / FT;       // 33 tiles (tile 32: g<3)
constexpr int RB      = 16;                         // r-values per block
constexpr int NBUF    = 2;
constexpr int NBLK    = 1024;                       // 4 blocks/CU

typedef float f4a __attribute__((ext_vector_type(4), aligned(16)));

__global__ __launch_bounds__(256, 4)
void oadd_kernel(const float* __restrict__ x, float* __restrict__ y) {
    // L[s][k][rl][j] = x[b, k*256 + rbase+rl, g0 + j - k]; wave w owns rl=4w..4w+3
    __shared__ float L[NBUF][4][RB][FT];            // 32768 B -> 4 blocks/CU

    const int tid  = threadIdx.x;
    const int w    = tid >> 6;         // wave 0..3 (owns rows 4w..4w+3)
    const int l    = tid & 63;
    const int bid  = blockIdx.x;
    const int q4   = bid >> 8;                      // 0..3: tile group
    const int b    = (bid >> 4) & 15;
    const int rsp  = bid & 15;
    const int rbase = rsp * RB;
    const int tile0 = (q4 == 0) ? 0 : 1 + q4 * 8;   // 0, 9, 17, 25
    const int T     = (q4 == 0) ? 9 : 8;            // tiles 0-8 / 9-16 / 17-24 / 25-32

    const float* __restrict__ xb = x + (size_t)b * WIN * NF;
    float* __restrict__ yb = y + (size_t)b * OUT_LEN;

    const int sr = l >> 4;             // row within the wave's 4-row slab
    const int c  = l & 15;             // 16B chunk within the 256B row window

    // fill: 4 fire-and-forget 1KB DMAs (one per k), all rows owned by THIS wave
    auto fill = [&](int t, int s) {
        const int tile = tile0 + t;
        const int g0   = tile * FT;
        #pragma unroll
        for (int k = 0; k < 4; ++k) {
            // last tile: clamp window to [NF-FT, NF), remapped in phase2.
            // tile 0, k>0: col<0 dips into previous row's tail (row>=256,
            // in-bounds garbage); masked in phase2.
            const int col0 = (tile == NT - 1) ? (NF - FT) : (g0 - k);
            const float* src = xb + (size_t)(k * HOP + rbase + w * 4 + sr) * NF
                                  + col0 + c * 4;
            __builtin_amdgcn_global_load_lds(
                (const __attribute__((address_space(1))) unsigned int*)src,
                (__attribute__((address_space(3))) unsigned int*)&L[s][k][w * 4][0],
                16, 0, 0);
        }
    };

    // phase2: k-sum + transpose-out, intra-wave only.
    // bank = g%32 -> 2 lanes/bank (free). Store: 16B/lane; the block's 4
    // waves complete one contiguous 64B y-line per g within the same CU.
    auto phase2 = [&](int t, int s) {
        const int tile = tile0 + t;
        const int g0   = tile * FT;
        if (tile == 0) {
            f4a v;
            #pragma unroll
            for (int m = 0; m < 4; ++m) {
                const int rl = w * 4 + m;
                float a = L[s][0][rl][l];
                if (l >= 1) a += L[s][1][rl][l];
                if (l >= 2) a += L[s][2][rl][l];
                if (l >= 3) a += L[s][3][rl][l];
                v[m] = a;
            }
            *reinterpret_cast<f4a*>(&yb[(size_t)(g0 + l) * HOP + rbase + w * 4]) = v;
        } else if (tile == NT - 1) {
            // valid g only for l<3; window [NF-FT,NF): f = g0+l-k -> idx FT-k+l
            if (l < 3) {
                f4a v;
                #pragma unroll
                for (int m = 0; m < 4; ++m) {
                    const int rl = w * 4 + m;
                    float a = 0.f;
                    #pragma unroll
                    for (int k = 1; k < 4; ++k)
                        if (k > l) a += L[s][k][rl][FT - k + l];
                    v[m] = a;
                }
                *reinterpret_cast<f4a*>(&yb[(size_t)(g0 + l) * HOP + rbase + w * 4]) = v;
            }
        } else {
            f4a v;
            #pragma unroll
            for (int m = 0; m < 4; ++m) {
                const int rl = w * 4 + m;
                v[m] = (L[s][0][rl][l] + L[s][1][rl][l])
                     + (L[s][2][rl][l] + L[s][3][rl][l]);
            }
            *reinterpret_cast<f4a*>(&yb[(size_t)(g0 + l) * HOP + rbase + w * 4]) = v;
        }
    };

    // ---- depth-1 per-wave pipeline, no barriers ----
    // per-wave vmem ops per iter: 4 DMA + 1 store.
    fill(0, 0);
    for (int t = 0; t < T; ++t) {
        if (t + 1 < T) fill(t + 1, (t + 1) & 1);
        // steady state at the wait, newest-first: D4(t+1), S(t-1), D4(t), ...
        // vmcnt(5) keeps D4(t+1)+S(t-1) in flight, guarantees D4(t) landed.
        if (t + 1 >= T)     asm volatile("s_waitcnt vmcnt(1)" ::: "memory");
        else if (t == 0)    asm volatile("s_waitcnt vmcnt(4)" ::: "memory");
        else                asm volatile("s_waitcnt vmcnt(5)" ::: "memory");
        phase2(t, t & 1);
    }
}

extern "C" void kernel_launch(void* const* d_in, const int* in_sizes, int n_in,
                              void* d_out, int out_size, void* d_ws, size_t ws_size,
                              hipStream_t stream) {
    const float* x = (const float*)d_in[0];
    float* y = (float*)d_out;
    oadd_kernel<<<dim3(NBLK), 256, 0, stream>>>(x, y);
}